// Round 1
// 108.207 us; speedup vs baseline: 1.0071x; 1.0071x over previous
//
#include <hip/hip_runtime.h>
#include <math.h>

#define NELEM   262144            // 4*64*32*32
#define NPAIRW  18432             // 64 o * 32 pairs * 9
#define PIMG    1296              // 36*36 padded image stride per (b,pair)
#define PPADN   165888            // 4*32*36*36 words
#define NPAIR   147968            // 4*32*34*34
#define EPS_BN  1e-5f
#define QSC     128.0f
#define QBIAS_F 16384.5f          // bias 16384 + 0.5 rounding
#define QZ_W    0x40004000u       // packed quantized zero
#define QINV    (1.0f / 128.0f)

// v_sad_u16: acc += |a.lo-b.lo| + |a.hi-b.hi|  (two terms per instruction)
__device__ __forceinline__ unsigned sad16(unsigned a, unsigned b, unsigned acc) {
    asm("v_sad_u16 %0, %1, %2, %0" : "+v"(acc) : "v"(a), "v"(b));
    return acc;
}
__device__ __forceinline__ unsigned qu(float v) {
    return (unsigned)(int)fmaf(v, QSC, QBIAS_F);
}

// ---------------------------------------------------------------------------
// prep: pair-packed quantized padded input qxp[4][32][36][36] (u16x2 words),
// qout1p halo words, pair-packed weights qw1p/qw2p, bn2 consts, sbuf zero.
// ---------------------------------------------------------------------------
__global__ __launch_bounds__(256) void prep_kernel(
    const float* __restrict__ x,
    const float* __restrict__ g1, const float* __restrict__ b1,
    const float* __restrict__ m1, const float* __restrict__ v1,
    const float* __restrict__ w1,
    const float* __restrict__ g2, const float* __restrict__ b2,
    const float* __restrict__ m2, const float* __restrict__ v2,
    const float* __restrict__ w2,
    unsigned* __restrict__ qxp, unsigned* __restrict__ qout1p,
    unsigned* __restrict__ qw1p, unsigned* __restrict__ qw2p,
    float* __restrict__ bn2c, float* __restrict__ sbuf)
{
    int i = blockIdx.x * 256 + threadIdx.x;
    if (i < NPAIR) {
        int bp  = i / 1156;                       // b*32 + pair
        int rc  = i - bp * 1156;
        int r   = rc / 34;
        int col = rc - r * 34;
        bool interior = (r > 0 && r < 33 && col > 0 && col < 33);
        unsigned q = QZ_W;
        if (interior) {
            int b  = bp >> 5;
            int c0 = (bp & 31) * 2;
            float inv0 = g1[c0] * rsqrtf(v1[c0] + EPS_BN);
            float bet0 = b1[c0] - m1[c0] * inv0;
            float inv1 = g1[c0 + 1] * rsqrtf(v1[c0 + 1] + EPS_BN);
            float bet1 = b1[c0 + 1] - m1[c0 + 1] * inv1;
            int off = (b * 64 + c0) * 1024 + (r - 1) * 32 + (col - 1);
            float a0 = fmaxf(fmaf(x[off],        inv0, bet0), 0.f);
            float a1 = fmaxf(fmaf(x[off + 1024], inv1, bet1), 0.f);
            q = qu(a0) | (qu(a1) << 16);
        }
        int pidx = bp * PIMG + r * 36 + col;
        qxp[pidx] = q;
        if (!interior) qout1p[pidx] = QZ_W;
        return;
    }
    int k = i - NPAIR;
    if (k < NPAIRW) {
        int o   = k / 288;
        int rem = k - o * 288;
        int pr  = rem / 9;
        int kk  = rem - pr * 9;
        int woff = (o * 64 + pr * 2) * 9 + kk;
        qw1p[k] = qu(w1[woff]) | (qu(w1[woff + 9]) << 16);
        return;
    }
    int l = k - NPAIRW;
    if (l < NPAIRW) {
        int o   = l / 288;
        int rem = l - o * 288;
        int pr  = rem / 9;
        int kk  = rem - pr * 9;
        int woff = (o * 64 + pr * 2) * 9 + kk;
        qw2p[l] = qu(w2[woff]) | (qu(w2[woff + 9]) << 16);
        return;
    }
    int m = l - NPAIRW;
    if (m < 64) {
        float inv = g2[m] * rsqrtf(v2[m] + EPS_BN);
        bn2c[m]      = -inv * QINV;               // maps u32 acc -> bn2 pre-act
        bn2c[m + 64] = b2[m] - m2[m] * inv;
        return;
    }
    int s = m - 64;
    if (s >= 0 && s < 256) sbuf[s] = 0.f;
}

// ---------------------------------------------------------------------------
// Adder2d on pair-packed u16 data (v_sad_u16). Re-tiled vs prior version:
// Grid 1024 = b(4) x og(32: 2 outputs) x sp(8: 4-row strips); 256 threads.
// pos = t&31: y_i = pos>>3 (0..3), x0 = (pos&7)*4 (4-wide); cq = t>>5 (0..7)
// -> 4 channel-pairs each (serial j loop, patch regs reused).
// Tail: ALL 256 threads produce one output each (2 o x 4 rows x 32 cols),
// 8-deep LDS reduction, red padded to stride 9 (9 coprime 32 -> no bank
// conflict on write, ~2-way on read vs 4-way before).
// __launch_bounds__(256,4): 128 VGPR budget (no spill risk), 4 blocks/CU
// co-resident = whole 1024-block grid in one round.
// MODE 0: writes quant(relu(bn2(-acc))) u16 half into packed qout.
// MODE 1: writes float out2 + SE spatial-sum atomics into sbuf.
// ---------------------------------------------------------------------------
template<int MODE>
__global__ __launch_bounds__(256, 4) void adder_kernel(
    const unsigned* __restrict__ qsrc, const unsigned* __restrict__ qwp,
    const float* __restrict__ bn2c,
    unsigned* __restrict__ qout, float* __restrict__ fout,
    float* __restrict__ sbuf)
{
    __shared__ unsigned wlds[2][32][12];     // 3072 B
    __shared__ unsigned red[8][32][9];       // 9216 B -> 12 KB total

    const int blk = blockIdx.x;
    const int sp  = blk & 7;                 // rows [sp*4, sp*4+4)
    const int og  = (blk >> 3) & 31;
    const int b   = blk >> 8;
    const int t   = threadIdx.x;
    const int pos = t & 31;
    const int cq  = t >> 5;                  // 0..7, 4 pairs each
    const int y_i = pos >> 3;                // 0..3
    const int x0  = (pos & 7) * 4;           // 0..28

    // weight staging: 2 o x 32 pairs x 9 words (~2.25 words/thread)
    for (int i = t; i < 576; i += 256) {
        int o_i = i / 288;
        int rem = i - o_i * 288;
        int pr  = rem / 9;
        int kk  = rem - pr * 9;
        wlds[o_i][pr][kk] = qwp[((og * 2 + o_i) * 32 + pr) * 9 + kk];
    }
    __syncthreads();

    unsigned acc[2][4];
#pragma unroll
    for (int oo = 0; oo < 2; ++oo)
#pragma unroll
        for (int xi = 0; xi < 4; ++xi) acc[oo][xi] = 0u;

#pragma unroll
    for (int j = 0; j < 4; ++j) {
        const int pr = cq * 4 + j;
        const unsigned* pc = qsrc + (size_t)(b * 32 + pr) * PIMG
                                  + (sp * 4 + y_i) * 36 + x0;
        unsigned p[3][6];                    // 6 words/row: x4 + x2 loads
#pragma unroll
        for (int r = 0; r < 3; ++r) {
            uint4 a0 = *reinterpret_cast<const uint4*>(pc + r * 36);
            uint2 a1 = *reinterpret_cast<const uint2*>(pc + r * 36 + 4);
            p[r][0] = a0.x; p[r][1] = a0.y; p[r][2] = a0.z; p[r][3] = a0.w;
            p[r][4] = a1.x; p[r][5] = a1.y;
        }
#pragma unroll
        for (int oo = 0; oo < 2; ++oo) {
            uint4 wa = *reinterpret_cast<const uint4*>(&wlds[oo][pr][0]);
            uint4 wb = *reinterpret_cast<const uint4*>(&wlds[oo][pr][4]);
            unsigned w8 = wlds[oo][pr][8];
            unsigned wv[9] = {wa.x, wa.y, wa.z, wa.w,
                              wb.x, wb.y, wb.z, wb.w, w8};
#pragma unroll
            for (int kh = 0; kh < 3; ++kh)
#pragma unroll
                for (int kw = 0; kw < 3; ++kw) {
                    unsigned ww = wv[kh * 3 + kw];
#pragma unroll
                    for (int xi = 0; xi < 4; ++xi)
                        acc[oo][xi] = sad16(p[kh][xi + kw], ww, acc[oo][xi]);
                }
        }
    }

    // ---- cq reduction via LDS (stride-9 padded: conflict-free writes) ----
    {
        unsigned* dst = &red[cq][pos][0];
#pragma unroll
        for (int z = 0; z < 8; ++z) dst[z] = acc[z >> 2][z & 3];
    }
    __syncthreads();

    // 256 outputs: 2 o x 4 rows x 32 cols — every thread produces one
    const int oo2 = t >> 7;                  // wave-pair uniform
    const int yy2 = (t >> 5) & 3;
    const int xx2 = t & 31;
    const int pp  = yy2 * 8 + (xx2 >> 2);
    const int z   = oo2 * 4 + (xx2 & 3);
    unsigned total = 0;
#pragma unroll
    for (int q = 0; q < 8; ++q) total += red[q][pp][z];

    const int o  = og * 2 + oo2;             // wave-uniform
    const int gy = sp * 4 + yy2;

    if (MODE == 0) {
        float a2 = fmaxf(fmaf((float)total, bn2c[o], bn2c[o + 64]), 0.f);
        unsigned short qv = (unsigned short)(int)fmaf(a2, QSC, QBIAS_F);
        size_t widx = (size_t)(b * 32 + (o >> 1)) * PIMG + (gy + 1) * 36 + (xx2 + 1);
        reinterpret_cast<unsigned short*>(qout)[widx * 2 + (o & 1)] = qv;
    } else {
        float v = -(float)total * QINV;
        fout[((b * 64 + o) * 32 + gy) * 32 + xx2] = v;
        float sum = v;                        // wave covers 2 rows of same o
#pragma unroll
        for (int off = 32; off > 0; off >>= 1)
            sum += __shfl_down(sum, off, 64);
        if ((t & 63) == 0) atomicAdd(&sbuf[b * 64 + o], sum);
    }
}

// ---------------------------------------------------------------------------
// SE gate + apply + shortcut. 256 blocks (one per b,o image) x 256 threads.
// ---------------------------------------------------------------------------
__global__ __launch_bounds__(256) void gate_kernel(
    const float* __restrict__ out2, const float* __restrict__ x,
    const float* __restrict__ sbuf,
    const float* __restrict__ fc1w, const float* __restrict__ fc1b,
    const float* __restrict__ fc2w, const float* __restrict__ fc2b,
    float* __restrict__ out)
{
    const int bo = blockIdx.x;
    const int b  = bo >> 6;
    const int o  = bo & 63;
    const int t  = threadIdx.x;

    __shared__ float ss[64];
    if (t < 64) ss[t] = sbuf[b * 64 + t] * (1.f / 1024.f);
    __syncthreads();

    float h[4];
#pragma unroll
    for (int j = 0; j < 4; ++j) {
        float a = fc1b[j];
#pragma unroll
        for (int c = 0; c < 64; ++c) a += ss[c] * fc1w[j * 64 + c];
        h[j] = fmaxf(a, 0.f);
    }
    float zz = fc2b[o];
#pragma unroll
    for (int j = 0; j < 4; ++j) zz += h[j] * fc2w[o * 4 + j];
    float g = 1.f / (1.f + __expf(-zz));

    const int base = bo * 1024 + t * 4;
    float4 v  = *reinterpret_cast<const float4*>(out2 + base);
    float4 xv = *reinterpret_cast<const float4*>(x + base);
    float4 r;
    r.x = v.x * g + xv.x;
    r.y = v.y * g + xv.y;
    r.z = v.z * g + xv.z;
    r.w = v.w * g + xv.w;
    *reinterpret_cast<float4*>(out + base) = r;
}

// ---------------------------------------------------------------------------
extern "C" void kernel_launch(void* const* d_in, const int* in_sizes, int n_in,
                              void* d_out, int out_size, void* d_ws, size_t ws_size,
                              hipStream_t stream)
{
    const float* x    = (const float*)d_in[0];
    const float* bn1g = (const float*)d_in[1];
    const float* bn1b = (const float*)d_in[2];
    const float* bn1m = (const float*)d_in[3];
    const float* bn1v = (const float*)d_in[4];
    const float* w1   = (const float*)d_in[5];
    const float* bn2g = (const float*)d_in[6];
    const float* bn2b = (const float*)d_in[7];
    const float* bn2m = (const float*)d_in[8];
    const float* bn2v = (const float*)d_in[9];
    const float* w2   = (const float*)d_in[10];
    const float* fc1w = (const float*)d_in[11];
    const float* fc1b = (const float*)d_in[12];
    const float* fc2w = (const float*)d_in[13];
    const float* fc2b = (const float*)d_in[14];

    unsigned* ws     = (unsigned*)d_ws;
    unsigned* qxp    = ws;                              // PPADN
    unsigned* qout1p = ws + PPADN;                      // PPADN
    float*    out2   = (float*)(ws + 2 * PPADN);        // NELEM
    unsigned* qw1p   = ws + 2 * PPADN + NELEM;          // NPAIRW
    unsigned* qw2p   = ws + 2 * PPADN + NELEM + NPAIRW; // NPAIRW
    float*    bn2c   = (float*)(ws + 2 * PPADN + NELEM + 2 * NPAIRW);        // 128
    float*    sbuf   = (float*)(ws + 2 * PPADN + NELEM + 2 * NPAIRW + 128);  // 256

    // segments: NPAIR + NPAIRW + NPAIRW + 64 + 256 = 185,152 -> 724 blocks
    prep_kernel<<<724, 256, 0, stream>>>(x, bn1g, bn1b, bn1m, bn1v, w1,
                                         bn2g, bn2b, bn2m, bn2v, w2,
                                         qxp, qout1p, qw1p, qw2p, bn2c, sbuf);
    adder_kernel<0><<<1024, 256, 0, stream>>>(qxp,    qw1p, bn2c, qout1p, nullptr, nullptr);
    adder_kernel<1><<<1024, 256, 0, stream>>>(qout1p, qw2p, nullptr, nullptr, out2, sbuf);
    gate_kernel<<<256, 256, 0, stream>>>(out2, x, sbuf, fc1w, fc1b, fc2w, fc2b,
                                         (float*)d_out);
}